// Round 8
// baseline (350.916 us; speedup 1.0000x reference)
//
#include <hip/hip_runtime.h>

// GraphSAGE 2-layer. N=40000, E=640000, 128 -> 512 (relu) -> 256.
// Round 8: register-prefetch B pipeline in the GEMM. Each thread owns one
// output column n (wave*64+lane); its weight row is contiguous -> per iter
// it preloads 4x16B of B(k+1) into VGPRs during compute of B(k), then
// ds_writes after the barrier (compiler's auto-vmcnt = the only wait,
// issued a full compute-phase early -> L2 latency hidden). Bt and Apan are
// kc-major with lane-contiguous 16B access (2-way bank alias = free).
// A-panel (64 x KT) still staged once per block. LDS 80/48 KB -> 2 blk/CU.

#define N_NODES 40000
#define N_EDGES 640000
#define F_IN 128
#define F_HID 512
#define F_OUT 256
#define NB_SCAN 157  // ceil(40000/256)

typedef unsigned short ushort_t;
typedef __attribute__((ext_vector_type(8))) short bf16x8;
typedef __attribute__((ext_vector_type(4))) float floatx4;

__device__ __forceinline__ ushort_t f2bf(float f) {
  union { float f; unsigned int u; } x; x.f = f;
  unsigned int r = (x.u + 0x7FFFu + ((x.u >> 16) & 1u)) >> 16;  // RNE
  return (ushort_t)r;
}
__device__ __forceinline__ float bf2f(ushort_t u) {
  union { unsigned int u; float f; } x; x.u = ((unsigned int)u) << 16;
  return x.f;
}

// ---------------- CSR build ----------------
__global__ void deg_kernel(const int* __restrict__ ei, int* __restrict__ deg) {
  int e = blockIdx.x * blockDim.x + threadIdx.x;
  if (e < N_EDGES) atomicAdd(&deg[ei[N_EDGES + e]], 1);
}

__global__ void scanA_kernel(const int* __restrict__ deg, int* __restrict__ bsum) {
  __shared__ int sdata[256];
  int i = blockIdx.x * 256 + threadIdx.x;
  sdata[threadIdx.x] = (i < N_NODES) ? deg[i] : 0;
  __syncthreads();
  #pragma unroll
  for (int off = 128; off > 0; off >>= 1) {
    if (threadIdx.x < off) sdata[threadIdx.x] += sdata[threadIdx.x + off];
    __syncthreads();
  }
  if (threadIdx.x == 0) bsum[blockIdx.x] = sdata[0];
}

__global__ void scanB_kernel(const int* __restrict__ bsum, int* __restrict__ boff) {
  __shared__ int buf[2][256];
  int tid = threadIdx.x;
  int v = (tid < NB_SCAN) ? bsum[tid] : 0;
  buf[0][tid] = v;
  __syncthreads();
  int cur = 0;
  #pragma unroll
  for (int off = 1; off < 256; off <<= 1) {
    int val = buf[cur][tid];
    if (tid >= off) val += buf[cur][tid - off];
    buf[cur ^ 1][tid] = val;
    __syncthreads();
    cur ^= 1;
  }
  if (tid < NB_SCAN) boff[tid] = buf[cur][tid] - v;  // exclusive
}

__global__ void scanC_kernel(const int* __restrict__ deg, const int* __restrict__ boff,
                             int* __restrict__ rowptr, int* __restrict__ cursor) {
  __shared__ int buf[2][256];
  int tid = threadIdx.x;
  int i = blockIdx.x * 256 + tid;
  int v = (i < N_NODES) ? deg[i] : 0;
  buf[0][tid] = v;
  __syncthreads();
  int cur = 0;
  #pragma unroll
  for (int off = 1; off < 256; off <<= 1) {
    int val = buf[cur][tid];
    if (tid >= off) val += buf[cur][tid - off];
    buf[cur ^ 1][tid] = val;
    __syncthreads();
    cur ^= 1;
  }
  if (i < N_NODES) {
    int ex = boff[blockIdx.x] + buf[cur][tid] - v;
    rowptr[i] = ex;
    cursor[i] = ex;
    if (i == N_NODES - 1) rowptr[N_NODES] = ex + v;  // == E
  }
}

__global__ void fill_kernel(const int* __restrict__ ei, int* __restrict__ cursor,
                            int* __restrict__ col) {
  int e = blockIdx.x * blockDim.x + threadIdx.x;
  if (e < N_EDGES) {
    int d = ei[N_EDGES + e];
    int s = ei[e];
    int pos = atomicAdd(&cursor[d], 1);
    col[pos] = s;
  }
}

// ---------------- conversions ----------------
__global__ void cvt_x_kernel(const float* __restrict__ x, ushort_t* __restrict__ xb) {
  int i = blockIdx.x * blockDim.x + threadIdx.x;  // per float4
  const int n4 = (N_NODES * F_IN) / 4;
  if (i < n4) {
    float4 v = ((const float4*)x)[i];
    ushort4 o;
    o.x = f2bf(v.x); o.y = f2bf(v.y); o.z = f2bf(v.z); o.w = f2bf(v.w);
    ((ushort4*)xb)[i] = o;
  }
}

// Wt[(rowoff+n)*ldt + koff + k] = bf16(W[k*N + n])  (transpose + convert + pack)
__global__ void wt_kernel(const float* __restrict__ W, ushort_t* __restrict__ Wt,
                          int K, int N, int rowoff, int koff, int ldt) {
  int i = blockIdx.x * blockDim.x + threadIdx.x;  // i = n*K + k (coalesced write)
  if (i < K * N) {
    int n = i / K, k = i - n * K;
    Wt[(size_t)(rowoff + n) * ldt + koff + k] = f2bf(W[(size_t)k * N + n]);
  }
}

__global__ void biascat_kernel(const float* __restrict__ b2, float* __restrict__ bc) {
  int i = threadIdx.x + blockIdx.x * blockDim.x;
  if (i < 512) bc[i] = (i < 256) ? 0.f : b2[i - 256];
}

// ---------------- aggregation ----------------
__global__ void agg1_kernel(const ushort_t* __restrict__ Xb, ushort_t* __restrict__ Yb,
                            const int* __restrict__ rowptr, const int* __restrict__ colidx) {
  __shared__ int cols[64];
  int n = blockIdx.x, f = threadIdx.x;
  int s = rowptr[n], e = rowptr[n + 1];
  float s0 = 0.f, s1 = 0.f;
  for (int base = s; base < e; base += 64) {
    int cnt = min(64, e - base);
    __syncthreads();
    if (f < cnt) cols[f] = colidx[base + f];
    __syncthreads();
    for (int j = 0; j < cnt; ++j) {
      unsigned int v = *(const unsigned int*)(Xb + (size_t)cols[j] * F_IN + 2 * f);
      s0 += bf2f((ushort_t)(v & 0xffffu));
      s1 += bf2f((ushort_t)(v >> 16));
    }
  }
  float inv = 1.f / fmaxf((float)(e - s), 1.f);
  unsigned int o = (unsigned int)f2bf(s0 * inv) | ((unsigned int)f2bf(s1 * inv) << 16);
  *(unsigned int*)(Yb + (size_t)n * F_IN + 2 * f) = o;
}

__global__ void agg2_kernel(const ushort_t* __restrict__ hl, const float* __restrict__ hr,
                            float* __restrict__ out,
                            const int* __restrict__ rowptr, const int* __restrict__ colidx) {
  __shared__ int cols[128];
  int n = blockIdx.x, f = threadIdx.x;
  int s = rowptr[n], e = rowptr[n + 1];
  float s0 = 0.f, s1 = 0.f;
  for (int base = s; base < e; base += 128) {
    int cnt = min(128, e - base);
    __syncthreads();
    if (f < cnt) cols[f] = colidx[base + f];
    __syncthreads();
    for (int j = 0; j < cnt; ++j) {
      unsigned int v = *(const unsigned int*)(hl + (size_t)cols[j] * F_OUT + 2 * f);
      s0 += bf2f((ushort_t)(v & 0xffffu));
      s1 += bf2f((ushort_t)(v >> 16));
    }
  }
  float inv = 1.f / fmaxf((float)(e - s), 1.f);
  float2 hrv = *(const float2*)(hr + (size_t)n * F_OUT + 2 * f);
  float2 o;
  o.x = s0 * inv + hrv.x;
  o.y = s1 * inv + hrv.y;
  *(float2*)(out + (size_t)n * F_OUT + 2 * f) = o;
}

// ---------------- bf16 MFMA GEMM, persistent A-panel + reg-prefetch B ----------------
// C[M, 512] = Acat[M, KT] @ Wcat[KT, 512] (+bias)(relu). Acat = [A0 | A1]
// when TWOPAIR. Wt transposed: Wt[n][k], row stride KT.
// BM=64, BN=256, BK=32, 256 threads (4 waves; wave w owns cols w*64..+63).
// Apan kc-major: chunk (kc,row) at (kc*64+row)*16B; staged once, lanes write
// consecutive rows (2-way bank alias = free). Bt kc-major: chunk (kc,n) at
// (kc*256+n)*16B. Per iter: ds_write breg (B(k), loaded last iter) -> sync ->
// prefetch B(k+1) into breg -> ds_read frags + 16 MFMA. The vmcnt wait sits
// at the ds_write, one compute-phase after issue -> L2 latency hidden.
template <bool TWOPAIR, bool RELU, bool BIAS, bool OUT_BF16, bool SPLITOUT, int KT>
__global__ __launch_bounds__(256) void gemm_mfma(
    const ushort_t* __restrict__ A0, const ushort_t* __restrict__ A1,
    const ushort_t* __restrict__ Wt, const float* __restrict__ bias,
    float* __restrict__ Cf, ushort_t* __restrict__ Cb, int M) {
  const int BM = 64, BN = 256, BK = 32;
  const int NKC = KT / 8;            // 16B chunks per A row
  __shared__ ushort_t Apan[64 * KT]; // kc-major
  __shared__ ushort_t Bt[BN * BK];   // kc-major
  const int tid = threadIdx.x;
  const int wave = tid >> 6, lane = tid & 63;
  const int lm = lane & 15, qk = lane >> 4;
  const int bn = blockIdx.x * BN;
  const int bm = blockIdx.y * BM;    // 625 * 64 = 40000 exactly, no tail
  const int K0 = TWOPAIR ? KT / 2 : KT;
  const int K0c = K0 / 8;

  // ---- stage A panel once; lanes cover consecutive rows (conflict-free) ----
  #pragma unroll
  for (int q = 0; q < (64 * NKC) / 256; ++q) {
    int c = tid + q * 256;
    int row = c & 63, kc = c >> 6;
    const ushort_t* src = (TWOPAIR && kc >= K0c)
        ? A1 + (size_t)(bm + row) * K0 + (kc - K0c) * 8
        : A0 + (size_t)(bm + row) * K0 + kc * 8;
    *(bf16x8*)(Apan + ((size_t)kc * 64 + row) * 8) = *(const bf16x8*)src;
  }

  // ---- B prefetch: thread owns col n = wave*64+lane; 64B/iter contiguous ----
  const int nown = wave * 64 + lane;
  const ushort_t* __restrict__ wrow = Wt + (size_t)(bn + nown) * KT;
  bf16x8 breg[4];
  #pragma unroll
  for (int kc = 0; kc < 4; ++kc) breg[kc] = *(const bf16x8*)(wrow + kc * 8);

  floatx4 acc[4][4] = {};
  for (int kb = 0; kb < KT; kb += BK) {
    __syncthreads();  // waves done reading Bt(k-1); also covers Apan staging
    #pragma unroll
    for (int kc = 0; kc < 4; ++kc)
      *(bf16x8*)(Bt + ((size_t)kc * 256 + nown) * 8) = breg[kc];
    __syncthreads();
    if (kb + BK < KT) {
      #pragma unroll
      for (int kc = 0; kc < 4; ++kc)
        breg[kc] = *(const bf16x8*)(wrow + (kb + BK) + kc * 8);
    }
    bf16x8 av[4], bv[4];
    #pragma unroll
    for (int mi = 0; mi < 4; ++mi)
      av[mi] = *(const bf16x8*)(Apan + ((size_t)(kb / 8 + qk) * 64 + mi * 16 + lm) * 8);
    #pragma unroll
    for (int ni = 0; ni < 4; ++ni)
      bv[ni] = *(const bf16x8*)(Bt + ((size_t)qk * 256 + wave * 64 + ni * 16 + lm) * 8);
    #pragma unroll
    for (int mi = 0; mi < 4; ++mi)
      #pragma unroll
      for (int ni = 0; ni < 4; ++ni)
        acc[mi][ni] = __builtin_amdgcn_mfma_f32_16x16x32_bf16(
            bv[ni], av[mi], acc[mi][ni], 0, 0, 0);  // swapped operands
  }

  // ---- epilogue: row = bm + mi*16 + lm, cols = bn + wave*64 + ni*16 + qk*4 ----
  #pragma unroll
  for (int ni = 0; ni < 4; ++ni) {
    int colg = bn + wave * 64 + ni * 16 + qk * 4;
    float4 b4 = {0.f, 0.f, 0.f, 0.f};
    if (BIAS) b4 = *(const float4*)&bias[colg];
    #pragma unroll
    for (int mi = 0; mi < 4; ++mi) {
      int rowg = bm + mi * 16 + lm;
      float v0 = acc[mi][ni][0] + b4.x;
      float v1 = acc[mi][ni][1] + b4.y;
      float v2 = acc[mi][ni][2] + b4.z;
      float v3 = acc[mi][ni][3] + b4.w;
      if (RELU) {
        v0 = fmaxf(v0, 0.f); v1 = fmaxf(v1, 0.f);
        v2 = fmaxf(v2, 0.f); v3 = fmaxf(v3, 0.f);
      }
      if (SPLITOUT) {
        if (colg < 256) {
          ushort4 o = {f2bf(v0), f2bf(v1), f2bf(v2), f2bf(v3)};
          *(ushort4*)&Cb[(size_t)rowg * 256 + colg] = o;
        } else {
          float4 o = {v0, v1, v2, v3};
          *(float4*)&Cf[(size_t)rowg * 256 + (colg - 256)] = o;
        }
      } else if (OUT_BF16) {
        ushort4 o = {f2bf(v0), f2bf(v1), f2bf(v2), f2bf(v3)};
        *(ushort4*)&Cb[(size_t)rowg * 512 + colg] = o;
      } else {
        float4 o = {v0, v1, v2, v3};
        *(float4*)&Cf[(size_t)rowg * 512 + colg] = o;
      }
    }
  }
}

extern "C" void kernel_launch(void* const* d_in, const int* in_sizes, int n_in,
                              void* d_out, int out_size, void* d_ws, size_t ws_size,
                              hipStream_t stream) {
  const float* x = (const float*)d_in[0];
  const int* ei = (const int*)d_in[1];  // int32 per harness, [2][E]
  const float* W1l = (const float*)d_in[2];
  const float* b1 = (const float*)d_in[3];
  const float* W1r = (const float*)d_in[4];
  const float* W2l = (const float*)d_in[5];
  const float* b2 = (const float*)d_in[6];
  const float* W2r = (const float*)d_in[7];
  float* out = (float*)d_out;

  char* ws = (char*)d_ws;
  size_t off = 0;
  auto alloc = [&](size_t bytes) {
    void* p = ws + off;
    off = (off + bytes + 255) & ~(size_t)255;
    return p;
  };
  int* deg = (int*)alloc((size_t)N_NODES * 4);
  int* rowptr = (int*)alloc((size_t)(N_NODES + 1) * 4);
  int* cursor = (int*)alloc((size_t)N_NODES * 4);
  int* col = (int*)alloc((size_t)N_EDGES * 4);
  int* bsum = (int*)alloc((size_t)NB_SCAN * 4);
  int* boff = (int*)alloc((size_t)NB_SCAN * 4);
  ushort_t* x_bf = (ushort_t*)alloc((size_t)N_NODES * F_IN * 2);
  ushort_t* aggx_bf = (ushort_t*)alloc((size_t)N_NODES * F_IN * 2);
  ushort_t* h_bf = (ushort_t*)alloc((size_t)N_NODES * F_HID * 2);
  ushort_t* hl_bf = (ushort_t*)alloc((size_t)N_NODES * F_OUT * 2);  // h@W2l, bf16
  float* hr = (float*)alloc((size_t)N_NODES * F_OUT * 4);           // h@W2r + b2
  ushort_t* Wcat1t = (ushort_t*)alloc((size_t)512 * 256 * 2);  // [512 n][W1l^T|W1r^T]
  ushort_t* Wcatt = (ushort_t*)alloc((size_t)512 * F_HID * 2); // [512 n][512 k]
  float* biascat = (float*)alloc(512 * 4);

  // CSR build
  hipMemsetAsync(deg, 0, (size_t)N_NODES * 4, stream);
  deg_kernel<<<(N_EDGES + 255) / 256, 256, 0, stream>>>(ei, deg);
  scanA_kernel<<<NB_SCAN, 256, 0, stream>>>(deg, bsum);
  scanB_kernel<<<1, 256, 0, stream>>>(bsum, boff);
  scanC_kernel<<<NB_SCAN, 256, 0, stream>>>(deg, boff, rowptr, cursor);
  fill_kernel<<<(N_EDGES + 255) / 256, 256, 0, stream>>>(ei, cursor, col);

  // Conversions (independent of CSR)
  cvt_x_kernel<<<(N_NODES * F_IN / 4 + 255) / 256, 256, 0, stream>>>(x, x_bf);
  wt_kernel<<<(F_IN * F_HID + 255) / 256, 256, 0, stream>>>(W1l, Wcat1t, 128, 512, 0, 0, 256);
  wt_kernel<<<(F_IN * F_HID + 255) / 256, 256, 0, stream>>>(W1r, Wcat1t, 128, 512, 0, 128, 256);
  wt_kernel<<<(F_HID * F_OUT + 255) / 256, 256, 0, stream>>>(W2l, Wcatt, 512, 256, 0, 0, 512);
  wt_kernel<<<(F_HID * F_OUT + 255) / 256, 256, 0, stream>>>(W2r, Wcatt, 512, 256, 256, 0, 512);
  biascat_kernel<<<2, 256, 0, stream>>>(b2, biascat);

  // Layer 1: aggx_bf = mean-agg(x_bf); h_bf = relu([aggx|x] @ [W1l;W1r] + b1)
  agg1_kernel<<<N_NODES, 64, 0, stream>>>(x_bf, aggx_bf, rowptr, col);
  gemm_mfma<true, true, true, true, false, 256>
      <<<dim3(2, N_NODES / 64), 256, 0, stream>>>(
          aggx_bf, x_bf, Wcat1t, b1, nullptr, h_bf, N_NODES);

  // Layer 2 fused: [hl_bf | hr] = h_bf @ [W2l|W2r] + [0|b2], split outputs
  gemm_mfma<false, false, true, false, true, 512>
      <<<dim3(2, N_NODES / 64), 256, 0, stream>>>(
          h_bf, nullptr, Wcatt, biascat, hr, hl_bf, N_NODES);
  // out = mean-agg(hl_bf) + hr
  agg2_kernel<<<N_NODES, 128, 0, stream>>>(hl_bf, hr, out, rowptr, col);
}